// Round 5
// baseline (427.512 us; speedup 1.0000x reference)
//
#include <hip/hip_runtime.h>
#include <hip/hip_bf16.h>

#define N_NODES 50000
#define N_EDGES 500000
#define D 256
#define K_TOT 768      // 3 * D
#define BK 32
#define NKT (K_TOT / BK)                     // 24
#define SCAN_N (3 * N_NODES)
#define SCAN_NBLK ((SCAN_N + 1023) / 1024)   // 147
#define NMT ((N_NODES + 31) / 32)            // 1563 M-strips of 32 rows
#define NPASS 7                              // dst>>13: 50000 < 7*8192

typedef __attribute__((ext_vector_type(8))) __bf16 bf16x8;
typedef __attribute__((ext_vector_type(4))) float f32x4;

__device__ __forceinline__ unsigned short f2bf(float f) {
    unsigned u = __builtin_bit_cast(unsigned, f);
    u += 0x7FFFu + ((u >> 16) & 1u);   // round-to-nearest-even
    return (unsigned short)(u >> 16);
}
__device__ __forceinline__ float bf2f(unsigned short h) {
    return __builtin_bit_cast(float, (unsigned)h << 16);
}

// ---------------- prep: zero cnt + W->bf16 transposed + feat->bf16 ----------------
__global__ void prep_kernel(const float* __restrict__ feat, unsigned short* __restrict__ fb,
                            const float* __restrict__ W0, const float* __restrict__ W1,
                            const float* __restrict__ W2, unsigned short* __restrict__ WT,
                            int* __restrict__ cnt) {
    int i = blockIdx.x * blockDim.x + threadIdx.x;
    if (i < N_NODES * D / 4) {                       // 3.2M float4 slots
        float4 v = ((const float4*)feat)[i];
        ushort4 pk;
        pk.x = f2bf(v.x); pk.y = f2bf(v.y); pk.z = f2bf(v.z); pk.w = f2bf(v.w);
        ((ushort4*)fb)[i] = pk;
    }
    if (i < D * K_TOT) {                             // WT[c][k], k = r*256+kin
        int c = i / K_TOT;
        int k = i - c * K_TOT;
        int r = k >> 8, kin = k & 255;
        const float* W = (r == 0) ? W0 : (r == 1) ? W1 : W2;
        WT[i] = f2bf(W[kin * D + c]);
    }
    if (i < SCAN_N / 4 + 1) {                        // zero cnt (150000 ints)
        if (i * 4 + 3 < SCAN_N) ((int4*)cnt)[i] = make_int4(0, 0, 0, 0);
        else for (int j = i * 4; j < SCAN_N; ++j) cnt[j] = 0;
    }
}

// ---------------- CSR build ----------------
__global__ void count_kernel(const int* __restrict__ d0, const int* __restrict__ d1,
                             const int* __restrict__ d2, int* __restrict__ cnt) {
    int i = blockIdx.x * blockDim.x + threadIdx.x;
    if (i >= 3 * N_EDGES) return;
    int r = i / N_EDGES;
    int e = i - r * N_EDGES;
    const int* d = (r == 0) ? d0 : (r == 1) ? d1 : d2;
    atomicAdd(&cnt[r * N_NODES + d[e]], 1);
}

// per-block exclusive scan; off/cur hold BLOCK-LOCAL offsets, bsum holds block totals
__global__ void scan1_kernel(const int* __restrict__ cnt, int* __restrict__ off,
                             int* __restrict__ cur, int* __restrict__ bsum) {
    __shared__ int wsum[16];
    int tid = threadIdx.x, lane = tid & 63, wid = tid >> 6;
    int i = blockIdx.x * 1024 + tid;
    int v = (i < SCAN_N) ? cnt[i] : 0;
    int x = v;
    #pragma unroll
    for (int d = 1; d < 64; d <<= 1) {
        int y = __shfl_up(x, d, 64);
        if (lane >= d) x += y;
    }
    if (lane == 63) wsum[wid] = x;
    __syncthreads();
    if (wid == 0 && lane < 16) {
        int s = wsum[lane];
        #pragma unroll
        for (int d = 1; d < 16; d <<= 1) {
            int y = __shfl_up(s, d, 64);
            if (lane >= d) s += y;
        }
        wsum[lane] = s;
    }
    __syncthreads();
    int wpre = wid ? wsum[wid - 1] : 0;
    int excl = x - v + wpre;
    if (i < SCAN_N) { off[i] = excl; cur[i] = excl; }
    if (tid == 1023) bsum[blockIdx.x] = x + wpre;
}

// exclusive scan of the 147 block sums (single block, in place)
__global__ void scan2_kernel(int* __restrict__ bsum) {
    __shared__ int wsum[16];
    int tid = threadIdx.x, lane = tid & 63, wid = tid >> 6;
    int v = (tid < SCAN_NBLK) ? bsum[tid] : 0;
    int x = v;
    #pragma unroll
    for (int d = 1; d < 64; d <<= 1) {
        int y = __shfl_up(x, d, 64);
        if (lane >= d) x += y;
    }
    if (lane == 63) wsum[wid] = x;
    __syncthreads();
    if (wid == 0 && lane < 16) {
        int s = wsum[lane];
        #pragma unroll
        for (int d = 1; d < 16; d <<= 1) {
            int y = __shfl_up(s, d, 64);
            if (lane >= d) s += y;
        }
        wsum[lane] = s;
    }
    __syncthreads();
    int wpre = wid ? wsum[wid - 1] : 0;
    if (tid < SCAN_NBLK) bsum[tid] = x - v + wpre;
}

// fill in NPASS dst-range passes (blockIdx.y = pass): confines the eidx scatter
// to ~1 MB hot window per pass so lines merge in L2 before eviction.
__global__ void fill_kernel(const int* __restrict__ s0, const int* __restrict__ d0,
                            const int* __restrict__ s1, const int* __restrict__ d1,
                            const int* __restrict__ s2, const int* __restrict__ d2,
                            int* __restrict__ cur, const int* __restrict__ bsum,
                            int* __restrict__ eidx) {
    int i = blockIdx.x * blockDim.x + threadIdx.x;
    if (i >= 3 * N_EDGES) return;
    int pass = blockIdx.y;
    int r = i / N_EDGES;
    int e = i - r * N_EDGES;
    const int* d = (r == 0) ? d0 : (r == 1) ? d1 : d2;
    int dd = d[e];
    if ((dd >> 13) != pass) return;
    const int* s = (r == 0) ? s0 : (r == 1) ? s1 : s2;
    int x = r * N_NODES + dd;
    int p = atomicAdd(&cur[x], 1) + bsum[x >> 10];
    eidx[p] = s[e];
}

// ---------------- per-node mean aggregation, all 3 relations per wave ----------------
__global__ void agg_kernel(const unsigned short* __restrict__ fb, const int* __restrict__ off,
                           const int* __restrict__ cnt, const int* __restrict__ bsum,
                           const int* __restrict__ eidx, unsigned short* __restrict__ agg) {
    int n = (blockIdx.x * blockDim.x + threadIdx.x) >> 6;
    int lane = threadIdx.x & 63;
    if (n >= N_NODES) return;
    const unsigned short* fbl = fb + lane * 4;

    int st3[3], dg3[3], e3[3];
    #pragma unroll
    for (int r = 0; r < 3; ++r) {
        int x = r * N_NODES + n;
        st3[r] = off[x] + bsum[x >> 10];
        dg3[r] = cnt[x];
    }
    #pragma unroll
    for (int r = 0; r < 3; ++r)                       // 3 head-loads in flight together
        e3[r] = (lane < dg3[r]) ? eidx[st3[r] + lane] : 0;

    #pragma unroll
    for (int r = 0; r < 3; ++r) {
        int deg = dg3[r], start = st3[r];
        float4 acc = make_float4(0.f, 0.f, 0.f, 0.f);
        for (int base = 0; base < deg; base += 64) {
            int m = min(deg - base, 64);
            int e = base ? ((lane < m) ? eidx[start + base + lane] : 0) : e3[r];
            int j = 0;
            for (; j + 7 < m; j += 8) {
                int t0 = __shfl(e, j + 0), t1 = __shfl(e, j + 1), t2 = __shfl(e, j + 2), t3 = __shfl(e, j + 3);
                int t4 = __shfl(e, j + 4), t5 = __shfl(e, j + 5), t6 = __shfl(e, j + 6), t7 = __shfl(e, j + 7);
                ushort4 v0 = *(const ushort4*)(fbl + (size_t)t0 * D);
                ushort4 v1 = *(const ushort4*)(fbl + (size_t)t1 * D);
                ushort4 v2 = *(const ushort4*)(fbl + (size_t)t2 * D);
                ushort4 v3 = *(const ushort4*)(fbl + (size_t)t3 * D);
                ushort4 v4 = *(const ushort4*)(fbl + (size_t)t4 * D);
                ushort4 v5 = *(const ushort4*)(fbl + (size_t)t5 * D);
                ushort4 v6 = *(const ushort4*)(fbl + (size_t)t6 * D);
                ushort4 v7 = *(const ushort4*)(fbl + (size_t)t7 * D);
                acc.x += ((bf2f(v0.x) + bf2f(v1.x)) + (bf2f(v2.x) + bf2f(v3.x))) + ((bf2f(v4.x) + bf2f(v5.x)) + (bf2f(v6.x) + bf2f(v7.x)));
                acc.y += ((bf2f(v0.y) + bf2f(v1.y)) + (bf2f(v2.y) + bf2f(v3.y))) + ((bf2f(v4.y) + bf2f(v5.y)) + (bf2f(v6.y) + bf2f(v7.y)));
                acc.z += ((bf2f(v0.z) + bf2f(v1.z)) + (bf2f(v2.z) + bf2f(v3.z))) + ((bf2f(v4.z) + bf2f(v5.z)) + (bf2f(v6.z) + bf2f(v7.z)));
                acc.w += ((bf2f(v0.w) + bf2f(v1.w)) + (bf2f(v2.w) + bf2f(v3.w))) + ((bf2f(v4.w) + bf2f(v5.w)) + (bf2f(v6.w) + bf2f(v7.w)));
            }
            for (; j < m; ++j) {
                int t = __shfl(e, j);
                ushort4 v = *(const ushort4*)(fbl + (size_t)t * D);
                acc.x += bf2f(v.x); acc.y += bf2f(v.y); acc.z += bf2f(v.z); acc.w += bf2f(v.w);
            }
        }
        float sc = (deg > 0) ? 1.0f / (float)deg : 0.0f;
        ushort4 pk;
        pk.x = f2bf(acc.x * sc);
        pk.y = f2bf(acc.y * sc);
        pk.z = f2bf(acc.z * sc);
        pk.w = f2bf(acc.w * sc);
        *(ushort4*)(agg + (((size_t)n * 3 + r) * D) + lane * 4) = pk;
    }
}

// ---------------- fused GEMM: out = relu( A[50000][768] @ B[768][256] + masked biases ) ----------------
// Barrier-free, LDS-free: each wave owns a 32x128 output tile, loads A/B fragments
// directly from global into registers (explicit 2-stage double buffer, full unroll
// so k-offsets fold into offset: immediates). Nothing for the compiler to drain.
__global__ __launch_bounds__(256) void gemm_kernel(
    const unsigned short* __restrict__ A, const unsigned short* __restrict__ BT,
    const int* __restrict__ cnt,
    const float* __restrict__ b0, const float* __restrict__ b1, const float* __restrict__ b2,
    float* __restrict__ out) {
    int lane = threadIdx.x & 63;
    int wid = (blockIdx.x * 256 + threadIdx.x) >> 6;   // 0..3127
    int mt = wid >> 1;                                  // 32-row strip
    int np = wid & 1;                                   // 128-col panel
    if (mt >= NMT) return;
    int rr = lane & 15, q = lane >> 4;

    int ar0 = mt * 32 + rr;            if (ar0 >= N_NODES) ar0 = N_NODES - 1;
    int ar1 = mt * 32 + 16 + rr;       if (ar1 >= N_NODES) ar1 = N_NODES - 1;
    const unsigned short* pa0 = A + (size_t)ar0 * K_TOT + q * 8;
    const unsigned short* pa1 = A + (size_t)ar1 * K_TOT + q * 8;
    const unsigned short* pb[8];
    #pragma unroll
    for (int nf = 0; nf < 8; ++nf)
        pb[nf] = BT + (size_t)(np * 128 + nf * 16 + rr) * K_TOT + q * 8;

    f32x4 acc[2][8] = {};
    bf16x8 a0[2], a1[2], bb[2][8];
    a0[0] = *(const bf16x8*)pa0;
    a1[0] = *(const bf16x8*)pa1;
    #pragma unroll
    for (int nf = 0; nf < 8; ++nf) bb[0][nf] = *(const bf16x8*)pb[nf];

    #pragma unroll
    for (int kt = 0; kt < NKT; ++kt) {
        int c = kt & 1, n = c ^ 1;
        if (kt + 1 < NKT) {
            a0[n] = *(const bf16x8*)(pa0 + (kt + 1) * BK);
            a1[n] = *(const bf16x8*)(pa1 + (kt + 1) * BK);
            #pragma unroll
            for (int nf = 0; nf < 8; ++nf)
                bb[n][nf] = *(const bf16x8*)(pb[nf] + (kt + 1) * BK);
        }
        #pragma unroll
        for (int nf = 0; nf < 8; ++nf) {
            acc[0][nf] = __builtin_amdgcn_mfma_f32_16x16x32_bf16(a0[c], bb[c][nf], acc[0][nf], 0, 0, 0);
            acc[1][nf] = __builtin_amdgcn_mfma_f32_16x16x32_bf16(a1[c], bb[c][nf], acc[1][nf], 0, 0, 0);
        }
    }

    // epilogue: masked biases + relu; C/D layout: col = lane&15, row = (lane>>4)*4 + reg
    #pragma unroll
    for (int mf = 0; mf < 2; ++mf) {
        #pragma unroll
        for (int rg = 0; rg < 4; ++rg) {
            int row = mt * 32 + mf * 16 + q * 4 + rg;
            if (row < N_NODES) {
                bool k0 = cnt[row] > 0;
                bool k1 = cnt[N_NODES + row] > 0;
                bool k2 = cnt[2 * N_NODES + row] > 0;
                #pragma unroll
                for (int nf = 0; nf < 8; ++nf) {
                    int col = np * 128 + nf * 16 + rr;
                    float v = acc[mf][nf][rg];
                    if (k0) v += b0[col];
                    if (k1) v += b1[col];
                    if (k2) v += b2[col];
                    out[(size_t)row * D + col] = fmaxf(v, 0.0f);
                }
            }
        }
    }
}

extern "C" void kernel_launch(void* const* d_in, const int* in_sizes, int n_in,
                              void* d_out, int out_size, void* d_ws, size_t ws_size,
                              hipStream_t stream) {
    const float* feat = (const float*)d_in[0];
    const int* src0 = (const int*)d_in[1];
    const int* dst0 = (const int*)d_in[2];
    const int* src1 = (const int*)d_in[3];
    const int* dst1 = (const int*)d_in[4];
    const int* src2 = (const int*)d_in[5];
    const int* dst2 = (const int*)d_in[6];
    const float* W0 = (const float*)d_in[7];
    const float* b0 = (const float*)d_in[8];
    const float* W1 = (const float*)d_in[9];
    const float* b1 = (const float*)d_in[10];
    const float* W2 = (const float*)d_in[11];
    const float* b2 = (const float*)d_in[12];
    float* out = (float*)d_out;

    char* ws = (char*)d_ws;
    size_t o = 0;
    auto alloc = [&](size_t bytes) {
        size_t r = o;
        o += (bytes + 255) & ~(size_t)255;
        return r;
    };
    int* cnt            = (int*)(ws + alloc((size_t)SCAN_N * 4));
    int* off            = (int*)(ws + alloc((size_t)SCAN_N * 4));
    int* cur            = (int*)(ws + alloc((size_t)SCAN_N * 4));
    int* bsum           = (int*)(ws + alloc((size_t)SCAN_NBLK * 4));
    int* eidx           = (int*)(ws + alloc(3ull * N_EDGES * 4));
    unsigned short* WT  = (unsigned short*)(ws + alloc((size_t)D * K_TOT * 2));
    unsigned short* fb  = (unsigned short*)(ws + alloc((size_t)N_NODES * D * 2));
    unsigned short* agg = (unsigned short*)(ws + alloc(3ull * N_NODES * D * 2));

    prep_kernel<<<(N_NODES * D / 4 + 255) / 256, 256, 0, stream>>>(feat, fb, W0, W1, W2, WT, cnt);
    count_kernel<<<(3 * N_EDGES + 255) / 256, 256, 0, stream>>>(dst0, dst1, dst2, cnt);
    scan1_kernel<<<SCAN_NBLK, 1024, 0, stream>>>(cnt, off, cur, bsum);
    scan2_kernel<<<1, 1024, 0, stream>>>(bsum);
    dim3 fg((3 * N_EDGES + 255) / 256, NPASS);
    fill_kernel<<<fg, 256, 0, stream>>>(src0, dst0, src1, dst1, src2, dst2, cur, bsum, eidx);
    agg_kernel<<<(N_NODES * 64 + 255) / 256, 256, 0, stream>>>(fb, off, cnt, bsum, eidx, agg);
    gemm_kernel<<<(NMT * 2 + 3) / 4, 256, 0, stream>>>(agg, WT, cnt, b0, b1, b2, out);
}

// Round 6
// 366.764 us; speedup vs baseline: 1.1656x; 1.1656x over previous
//
#include <hip/hip_runtime.h>
#include <hip/hip_bf16.h>

#define N_NODES 50000
#define N_EDGES 500000
#define D 256
#define K_TOT 768      // 3 * D
#define M_TILE 128
#define N_TILE 128
#define BK 32
#define NKT (K_TOT / BK)                     // 24
#define SCAN_N (3 * N_NODES)
#define SCAN_NBLK ((SCAN_N + 1023) / 1024)   // 147
#define NPASS 7                              // dst>>13: 50000 < 7*8192

typedef __attribute__((ext_vector_type(8))) __bf16 bf16x8;
typedef __attribute__((ext_vector_type(4))) float f32x4;

__device__ __forceinline__ unsigned short f2bf(float f) {
    unsigned u = __builtin_bit_cast(unsigned, f);
    u += 0x7FFFu + ((u >> 16) & 1u);   // round-to-nearest-even
    return (unsigned short)(u >> 16);
}
__device__ __forceinline__ float bf2f(unsigned short h) {
    return __builtin_bit_cast(float, (unsigned)h << 16);
}
__device__ __forceinline__ void gload16(const unsigned short* g, __bf16* l) {
    __builtin_amdgcn_global_load_lds(
        (const __attribute__((address_space(1))) void*)g,
        (__attribute__((address_space(3))) void*)l, 16, 0, 0);
}

// ---------------- prep: zero cnt + W->bf16 transposed + feat->bf16 ----------------
__global__ void prep_kernel(const float* __restrict__ feat, unsigned short* __restrict__ fb,
                            const float* __restrict__ W0, const float* __restrict__ W1,
                            const float* __restrict__ W2, unsigned short* __restrict__ WT,
                            int* __restrict__ cnt) {
    int i = blockIdx.x * blockDim.x + threadIdx.x;
    if (i < N_NODES * D / 4) {                       // 3.2M float4 slots
        float4 v = ((const float4*)feat)[i];
        ushort4 pk;
        pk.x = f2bf(v.x); pk.y = f2bf(v.y); pk.z = f2bf(v.z); pk.w = f2bf(v.w);
        ((ushort4*)fb)[i] = pk;
    }
    if (i < D * K_TOT) {                             // WT[c][k], k = r*256+kin
        int c = i / K_TOT;
        int k = i - c * K_TOT;
        int r = k >> 8, kin = k & 255;
        const float* W = (r == 0) ? W0 : (r == 1) ? W1 : W2;
        WT[i] = f2bf(W[kin * D + c]);
    }
    if (i < SCAN_N / 4 + 1) {                        // zero cnt (150000 ints)
        if (i * 4 + 3 < SCAN_N) ((int4*)cnt)[i] = make_int4(0, 0, 0, 0);
        else for (int j = i * 4; j < SCAN_N; ++j) cnt[j] = 0;
    }
}

// ---------------- CSR build ----------------
__global__ void count_kernel(const int* __restrict__ d0, const int* __restrict__ d1,
                             const int* __restrict__ d2, int* __restrict__ cnt) {
    int i = blockIdx.x * blockDim.x + threadIdx.x;
    if (i >= 3 * N_EDGES) return;
    int r = i / N_EDGES;
    int e = i - r * N_EDGES;
    const int* d = (r == 0) ? d0 : (r == 1) ? d1 : d2;
    atomicAdd(&cnt[r * N_NODES + d[e]], 1);
}

// per-block exclusive scan; off/cur hold BLOCK-LOCAL offsets, bsum holds block totals
__global__ void scan1_kernel(const int* __restrict__ cnt, int* __restrict__ off,
                             int* __restrict__ cur, int* __restrict__ bsum) {
    __shared__ int wsum[16];
    int tid = threadIdx.x, lane = tid & 63, wid = tid >> 6;
    int i = blockIdx.x * 1024 + tid;
    int v = (i < SCAN_N) ? cnt[i] : 0;
    int x = v;
    #pragma unroll
    for (int d = 1; d < 64; d <<= 1) {
        int y = __shfl_up(x, d, 64);
        if (lane >= d) x += y;
    }
    if (lane == 63) wsum[wid] = x;
    __syncthreads();
    if (wid == 0 && lane < 16) {
        int s = wsum[lane];
        #pragma unroll
        for (int d = 1; d < 16; d <<= 1) {
            int y = __shfl_up(s, d, 64);
            if (lane >= d) s += y;
        }
        wsum[lane] = s;
    }
    __syncthreads();
    int wpre = wid ? wsum[wid - 1] : 0;
    int excl = x - v + wpre;
    if (i < SCAN_N) { off[i] = excl; cur[i] = excl; }
    if (tid == 1023) bsum[blockIdx.x] = x + wpre;
}

// exclusive scan of the 147 block sums (single block, in place)
__global__ void scan2_kernel(int* __restrict__ bsum) {
    __shared__ int wsum[16];
    int tid = threadIdx.x, lane = tid & 63, wid = tid >> 6;
    int v = (tid < SCAN_NBLK) ? bsum[tid] : 0;
    int x = v;
    #pragma unroll
    for (int d = 1; d < 64; d <<= 1) {
        int y = __shfl_up(x, d, 64);
        if (lane >= d) x += y;
    }
    if (lane == 63) wsum[wid] = x;
    __syncthreads();
    if (wid == 0 && lane < 16) {
        int s = wsum[lane];
        #pragma unroll
        for (int d = 1; d < 16; d <<= 1) {
            int y = __shfl_up(s, d, 64);
            if (lane >= d) s += y;
        }
        wsum[lane] = s;
    }
    __syncthreads();
    int wpre = wid ? wsum[wid - 1] : 0;
    if (tid < SCAN_NBLK) bsum[tid] = x - v + wpre;
}

// fill in NPASS dst-range passes (blockIdx.y = pass): confines the eidx scatter
// to ~1 MB hot window per pass so lines merge in L2 before eviction.
__global__ void fill_kernel(const int* __restrict__ s0, const int* __restrict__ d0,
                            const int* __restrict__ s1, const int* __restrict__ d1,
                            const int* __restrict__ s2, const int* __restrict__ d2,
                            int* __restrict__ cur, const int* __restrict__ bsum,
                            int* __restrict__ eidx) {
    int i = blockIdx.x * blockDim.x + threadIdx.x;
    if (i >= 3 * N_EDGES) return;
    int pass = blockIdx.y;
    int r = i / N_EDGES;
    int e = i - r * N_EDGES;
    const int* d = (r == 0) ? d0 : (r == 1) ? d1 : d2;
    int dd = d[e];
    if ((dd >> 13) != pass) return;
    const int* s = (r == 0) ? s0 : (r == 1) ? s1 : s2;
    int x = r * N_NODES + dd;
    int p = atomicAdd(&cur[x], 1) + bsum[x >> 10];
    eidx[p] = s[e];
}

// ---------------- per-node mean aggregation, all 3 relations per wave ----------------
__global__ void agg_kernel(const unsigned short* __restrict__ fb, const int* __restrict__ off,
                           const int* __restrict__ cnt, const int* __restrict__ bsum,
                           const int* __restrict__ eidx, unsigned short* __restrict__ agg) {
    int n = (blockIdx.x * blockDim.x + threadIdx.x) >> 6;
    int lane = threadIdx.x & 63;
    if (n >= N_NODES) return;
    const unsigned short* fbl = fb + lane * 4;

    int st3[3], dg3[3], e3[3];
    #pragma unroll
    for (int r = 0; r < 3; ++r) {
        int x = r * N_NODES + n;
        st3[r] = off[x] + bsum[x >> 10];
        dg3[r] = cnt[x];
    }
    #pragma unroll
    for (int r = 0; r < 3; ++r)                       // 3 head-loads in flight together
        e3[r] = (lane < dg3[r]) ? eidx[st3[r] + lane] : 0;

    #pragma unroll
    for (int r = 0; r < 3; ++r) {
        int deg = dg3[r], start = st3[r];
        float4 acc = make_float4(0.f, 0.f, 0.f, 0.f);
        for (int base = 0; base < deg; base += 64) {
            int m = min(deg - base, 64);
            int e = base ? ((lane < m) ? eidx[start + base + lane] : 0) : e3[r];
            int j = 0;
            for (; j + 7 < m; j += 8) {
                int t0 = __shfl(e, j + 0), t1 = __shfl(e, j + 1), t2 = __shfl(e, j + 2), t3 = __shfl(e, j + 3);
                int t4 = __shfl(e, j + 4), t5 = __shfl(e, j + 5), t6 = __shfl(e, j + 6), t7 = __shfl(e, j + 7);
                ushort4 v0 = *(const ushort4*)(fbl + (size_t)t0 * D);
                ushort4 v1 = *(const ushort4*)(fbl + (size_t)t1 * D);
                ushort4 v2 = *(const ushort4*)(fbl + (size_t)t2 * D);
                ushort4 v3 = *(const ushort4*)(fbl + (size_t)t3 * D);
                ushort4 v4 = *(const ushort4*)(fbl + (size_t)t4 * D);
                ushort4 v5 = *(const ushort4*)(fbl + (size_t)t5 * D);
                ushort4 v6 = *(const ushort4*)(fbl + (size_t)t6 * D);
                ushort4 v7 = *(const ushort4*)(fbl + (size_t)t7 * D);
                acc.x += ((bf2f(v0.x) + bf2f(v1.x)) + (bf2f(v2.x) + bf2f(v3.x))) + ((bf2f(v4.x) + bf2f(v5.x)) + (bf2f(v6.x) + bf2f(v7.x)));
                acc.y += ((bf2f(v0.y) + bf2f(v1.y)) + (bf2f(v2.y) + bf2f(v3.y))) + ((bf2f(v4.y) + bf2f(v5.y)) + (bf2f(v6.y) + bf2f(v7.y)));
                acc.z += ((bf2f(v0.z) + bf2f(v1.z)) + (bf2f(v2.z) + bf2f(v3.z))) + ((bf2f(v4.z) + bf2f(v5.z)) + (bf2f(v6.z) + bf2f(v7.z)));
                acc.w += ((bf2f(v0.w) + bf2f(v1.w)) + (bf2f(v2.w) + bf2f(v3.w))) + ((bf2f(v4.w) + bf2f(v5.w)) + (bf2f(v6.w) + bf2f(v7.w)));
            }
            for (; j < m; ++j) {
                int t = __shfl(e, j);
                ushort4 v = *(const ushort4*)(fbl + (size_t)t * D);
                acc.x += bf2f(v.x); acc.y += bf2f(v.y); acc.z += bf2f(v.z); acc.w += bf2f(v.w);
            }
        }
        float sc = (deg > 0) ? 1.0f / (float)deg : 0.0f;
        ushort4 pk;
        pk.x = f2bf(acc.x * sc);
        pk.y = f2bf(acc.y * sc);
        pk.z = f2bf(acc.z * sc);
        pk.w = f2bf(acc.w * sc);
        *(ushort4*)(agg + (((size_t)n * 3 + r) * D) + lane * 4) = pk;
    }
}

// ---------------- fused GEMM: out = relu( A[50000][768] @ B[768][256] + masked biases ) ----------------
// 3-buffer LDS pipeline, K-loop FULLY UNROLLED so all buffer indices are static LDS
// offsets -> compiler alias analysis can keep global_load_lds in flight across steps
// (counted vmcnt, never 0 until tail). One barrier/step is WAR-safe with 3 buffers.
// Bank-swizzle: seg' = seg ^ ((row>>1)&3), both sides (round-3 verified, conflicts=0).
__global__ __launch_bounds__(256) void gemm_kernel(
    const unsigned short* __restrict__ A, const unsigned short* __restrict__ BT,
    const int* __restrict__ cnt,
    const float* __restrict__ b0, const float* __restrict__ b1, const float* __restrict__ b2,
    float* __restrict__ out) {
    __shared__ __bf16 Asl[3][M_TILE][BK];   // 3 x 8 KB
    __shared__ __bf16 Bsl[3][N_TILE][BK];   // 3 x 8 KB
    int tid = threadIdx.x;
    int lane = tid & 63, w = tid >> 6;
    int wr = w >> 1, wc = w & 1;
    int m0 = blockIdx.y * M_TILE;
    int c0 = blockIdx.x * N_TILE;
    f32x4 acc[4][4] = {};

    int s_lo = w * 64 + lane;                            // 16B slot, stage half 0
    int row_lo = s_lo >> 2, row_hi = (s_lo + 256) >> 2;
    int seg_lo = (s_lo & 3) ^ ((row_lo >> 1) & 3);       // inverse-swizzled global seg
    int seg_hi = (s_lo & 3) ^ ((row_hi >> 1) & 3);
    int gma = m0 + row_lo; if (gma >= N_NODES) gma = N_NODES - 1;
    int gmb = m0 + row_hi; if (gmb >= N_NODES) gmb = N_NODES - 1;
    const unsigned short* ga_lo = A + (size_t)gma * K_TOT + seg_lo * 8;
    const unsigned short* ga_hi = A + (size_t)gmb * K_TOT + seg_hi * 8;
    const unsigned short* gb_lo = BT + (size_t)(c0 + row_lo) * K_TOT + seg_lo * 8;
    const unsigned short* gb_hi = BT + (size_t)(c0 + row_hi) * K_TOT + seg_hi * 8;

    auto stage = [&](int kt, int b) {                    // b is compile-time after unroll
        gload16(ga_lo + kt * BK, &Asl[b][0][0] + (size_t)s_lo * 8);
        gload16(ga_hi + kt * BK, &Asl[b][0][0] + (size_t)(s_lo + 256) * 8);
        gload16(gb_lo + kt * BK, &Bsl[b][0][0] + (size_t)s_lo * 8);
        gload16(gb_hi + kt * BK, &Bsl[b][0][0] + (size_t)(s_lo + 256) * 8);
    };

    stage(0, 0);          // 4 vm instrs / wave
    stage(1, 1);          // 8 outstanding
    int q = lane >> 4;
    int rr = lane & 15;
    #pragma unroll
    for (int kt = 0; kt < NKT; ++kt) {
        if (kt + 1 < NKT) asm volatile("s_waitcnt vmcnt(4)" ::: "memory");  // kt landed, kt+1 in flight
        else              asm volatile("s_waitcnt vmcnt(0)" ::: "memory");  // tail
        __builtin_amdgcn_s_barrier();                    // all waves' kt loads landed
        int b = kt % 3;                                  // static after unroll
        bf16x8 af[4], bfr[4];
        #pragma unroll
        for (int mf = 0; mf < 4; ++mf) {
            int row = wr * 64 + mf * 16 + rr;
            af[mf] = *(const bf16x8*)&Asl[b][row][(q ^ ((row >> 1) & 3)) * 8];
        }
        #pragma unroll
        for (int nf = 0; nf < 4; ++nf) {
            int row = wc * 64 + nf * 16 + rr;
            bfr[nf] = *(const bf16x8*)&Bsl[b][row][(q ^ ((row >> 1) & 3)) * 8];
        }
        if (kt + 2 < NKT) stage(kt + 2, (kt + 2) % 3);   // re-fill the pipe
        #pragma unroll
        for (int mf = 0; mf < 4; ++mf)
            #pragma unroll
            for (int nf = 0; nf < 4; ++nf)
                acc[mf][nf] = __builtin_amdgcn_mfma_f32_16x16x32_bf16(af[mf], bfr[nf], acc[mf][nf], 0, 0, 0);
    }

    // epilogue: masked biases + relu; C/D layout: col = lane&15, row = (lane>>4)*4 + reg
    #pragma unroll
    for (int mf = 0; mf < 4; ++mf) {
        #pragma unroll
        for (int nf = 0; nf < 4; ++nf) {
            int col = c0 + wc * 64 + nf * 16 + (lane & 15);
            #pragma unroll
            for (int reg = 0; reg < 4; ++reg) {
                int row = m0 + wr * 64 + mf * 16 + ((lane >> 4) * 4) + reg;
                if (row < N_NODES) {
                    float v = acc[mf][nf][reg];
                    if (cnt[row] > 0)               v += b0[col];
                    if (cnt[N_NODES + row] > 0)     v += b1[col];
                    if (cnt[2 * N_NODES + row] > 0) v += b2[col];
                    out[(size_t)row * D + col] = fmaxf(v, 0.0f);
                }
            }
        }
    }
}

extern "C" void kernel_launch(void* const* d_in, const int* in_sizes, int n_in,
                              void* d_out, int out_size, void* d_ws, size_t ws_size,
                              hipStream_t stream) {
    const float* feat = (const float*)d_in[0];
    const int* src0 = (const int*)d_in[1];
    const int* dst0 = (const int*)d_in[2];
    const int* src1 = (const int*)d_in[3];
    const int* dst1 = (const int*)d_in[4];
    const int* src2 = (const int*)d_in[5];
    const int* dst2 = (const int*)d_in[6];
    const float* W0 = (const float*)d_in[7];
    const float* b0 = (const float*)d_in[8];
    const float* W1 = (const float*)d_in[9];
    const float* b1 = (const float*)d_in[10];
    const float* W2 = (const float*)d_in[11];
    const float* b2 = (const float*)d_in[12];
    float* out = (float*)d_out;

    char* ws = (char*)d_ws;
    size_t o = 0;
    auto alloc = [&](size_t bytes) {
        size_t r = o;
        o += (bytes + 255) & ~(size_t)255;
        return r;
    };
    int* cnt            = (int*)(ws + alloc((size_t)SCAN_N * 4));
    int* off            = (int*)(ws + alloc((size_t)SCAN_N * 4));
    int* cur            = (int*)(ws + alloc((size_t)SCAN_N * 4));
    int* bsum           = (int*)(ws + alloc((size_t)SCAN_NBLK * 4));
    int* eidx           = (int*)(ws + alloc(3ull * N_EDGES * 4));
    unsigned short* WT  = (unsigned short*)(ws + alloc((size_t)D * K_TOT * 2));
    unsigned short* fb  = (unsigned short*)(ws + alloc((size_t)N_NODES * D * 2));
    unsigned short* agg = (unsigned short*)(ws + alloc(3ull * N_NODES * D * 2));

    prep_kernel<<<(N_NODES * D / 4 + 255) / 256, 256, 0, stream>>>(feat, fb, W0, W1, W2, WT, cnt);
    count_kernel<<<(3 * N_EDGES + 255) / 256, 256, 0, stream>>>(dst0, dst1, dst2, cnt);
    scan1_kernel<<<SCAN_NBLK, 1024, 0, stream>>>(cnt, off, cur, bsum);
    scan2_kernel<<<1, 1024, 0, stream>>>(bsum);
    dim3 fg((3 * N_EDGES + 255) / 256, NPASS);
    fill_kernel<<<fg, 256, 0, stream>>>(src0, dst0, src1, dst1, src2, dst2, cur, bsum, eidx);
    agg_kernel<<<(N_NODES * 64 + 255) / 256, 256, 0, stream>>>(fb, off, cnt, bsum, eidx, agg);
    dim3 g(D / N_TILE, (N_NODES + M_TILE - 1) / M_TILE);
    gemm_kernel<<<g, 256, 0, stream>>>(agg, WT, cnt, b0, b1, b2, out);
}

// Round 7
// 357.000 us; speedup vs baseline: 1.1975x; 1.0273x over previous
//
#include <hip/hip_runtime.h>
#include <hip/hip_bf16.h>

#define N_NODES 50000
#define N_EDGES 500000
#define D 256
#define K_TOT 768      // 3 * D
#define M_TILE 256
#define N_TILE 256
#define BK 32
#define NKT (K_TOT / BK)                     // 24
#define SCAN_N (3 * N_NODES)
#define SCAN_NBLK ((SCAN_N + 1023) / 1024)   // 147
#define NPASS 7                              // dst>>13: 50000 < 7*8192
#define NMB ((N_NODES + M_TILE - 1) / M_TILE)  // 196 blocks, single generation

typedef __attribute__((ext_vector_type(8))) __bf16 bf16x8;
typedef __attribute__((ext_vector_type(4))) float f32x4;

__device__ __forceinline__ unsigned short f2bf(float f) {
    unsigned u = __builtin_bit_cast(unsigned, f);
    u += 0x7FFFu + ((u >> 16) & 1u);   // round-to-nearest-even
    return (unsigned short)(u >> 16);
}
__device__ __forceinline__ float bf2f(unsigned short h) {
    return __builtin_bit_cast(float, (unsigned)h << 16);
}
__device__ __forceinline__ void gload16(const unsigned short* g, __bf16* l) {
    __builtin_amdgcn_global_load_lds(
        (const __attribute__((address_space(1))) void*)g,
        (__attribute__((address_space(3))) void*)l, 16, 0, 0);
}

// ---------------- prep: zero cnt + W->bf16 transposed + feat->bf16 ----------------
__global__ void prep_kernel(const float* __restrict__ feat, unsigned short* __restrict__ fb,
                            const float* __restrict__ W0, const float* __restrict__ W1,
                            const float* __restrict__ W2, unsigned short* __restrict__ WT,
                            int* __restrict__ cnt) {
    int i = blockIdx.x * blockDim.x + threadIdx.x;
    if (i < N_NODES * D / 4) {                       // 3.2M float4 slots
        float4 v = ((const float4*)feat)[i];
        ushort4 pk;
        pk.x = f2bf(v.x); pk.y = f2bf(v.y); pk.z = f2bf(v.z); pk.w = f2bf(v.w);
        ((ushort4*)fb)[i] = pk;
    }
    if (i < D * K_TOT) {                             // WT[c][k], k = r*256+kin
        int c = i / K_TOT;
        int k = i - c * K_TOT;
        int r = k >> 8, kin = k & 255;
        const float* W = (r == 0) ? W0 : (r == 1) ? W1 : W2;
        WT[i] = f2bf(W[kin * D + c]);
    }
    if (i < SCAN_N / 4 + 1) {                        // zero cnt (150000 ints)
        if (i * 4 + 3 < SCAN_N) ((int4*)cnt)[i] = make_int4(0, 0, 0, 0);
        else for (int j = i * 4; j < SCAN_N; ++j) cnt[j] = 0;
    }
}

// ---------------- CSR build ----------------
__global__ void count_kernel(const int* __restrict__ d0, const int* __restrict__ d1,
                             const int* __restrict__ d2, int* __restrict__ cnt) {
    int i = blockIdx.x * blockDim.x + threadIdx.x;
    if (i >= 3 * N_EDGES) return;
    int r = i / N_EDGES;
    int e = i - r * N_EDGES;
    const int* d = (r == 0) ? d0 : (r == 1) ? d1 : d2;
    atomicAdd(&cnt[r * N_NODES + d[e]], 1);
}

// per-block exclusive scan; off/cur hold BLOCK-LOCAL offsets, bsum holds block totals
__global__ void scan1_kernel(const int* __restrict__ cnt, int* __restrict__ off,
                             int* __restrict__ cur, int* __restrict__ bsum) {
    __shared__ int wsum[16];
    int tid = threadIdx.x, lane = tid & 63, wid = tid >> 6;
    int i = blockIdx.x * 1024 + tid;
    int v = (i < SCAN_N) ? cnt[i] : 0;
    int x = v;
    #pragma unroll
    for (int d = 1; d < 64; d <<= 1) {
        int y = __shfl_up(x, d, 64);
        if (lane >= d) x += y;
    }
    if (lane == 63) wsum[wid] = x;
    __syncthreads();
    if (wid == 0 && lane < 16) {
        int s = wsum[lane];
        #pragma unroll
        for (int d = 1; d < 16; d <<= 1) {
            int y = __shfl_up(s, d, 64);
            if (lane >= d) s += y;
        }
        wsum[lane] = s;
    }
    __syncthreads();
    int wpre = wid ? wsum[wid - 1] : 0;
    int excl = x - v + wpre;
    if (i < SCAN_N) { off[i] = excl; cur[i] = excl; }
    if (tid == 1023) bsum[blockIdx.x] = x + wpre;
}

// exclusive scan of the 147 block sums (single block, in place)
__global__ void scan2_kernel(int* __restrict__ bsum) {
    __shared__ int wsum[16];
    int tid = threadIdx.x, lane = tid & 63, wid = tid >> 6;
    int v = (tid < SCAN_NBLK) ? bsum[tid] : 0;
    int x = v;
    #pragma unroll
    for (int d = 1; d < 64; d <<= 1) {
        int y = __shfl_up(x, d, 64);
        if (lane >= d) x += y;
    }
    if (lane == 63) wsum[wid] = x;
    __syncthreads();
    if (wid == 0 && lane < 16) {
        int s = wsum[lane];
        #pragma unroll
        for (int d = 1; d < 16; d <<= 1) {
            int y = __shfl_up(s, d, 64);
            if (lane >= d) s += y;
        }
        wsum[lane] = s;
    }
    __syncthreads();
    int wpre = wid ? wsum[wid - 1] : 0;
    if (tid < SCAN_NBLK) bsum[tid] = x - v + wpre;
}

// fill in NPASS dst-range passes (blockIdx.y = pass): confines the eidx scatter
// to ~1 MB hot window per pass so lines merge in L2 before eviction.
__global__ void fill_kernel(const int* __restrict__ s0, const int* __restrict__ d0,
                            const int* __restrict__ s1, const int* __restrict__ d1,
                            const int* __restrict__ s2, const int* __restrict__ d2,
                            int* __restrict__ cur, const int* __restrict__ bsum,
                            int* __restrict__ eidx) {
    int i = blockIdx.x * blockDim.x + threadIdx.x;
    if (i >= 3 * N_EDGES) return;
    int pass = blockIdx.y;
    int r = i / N_EDGES;
    int e = i - r * N_EDGES;
    const int* d = (r == 0) ? d0 : (r == 1) ? d1 : d2;
    int dd = d[e];
    if ((dd >> 13) != pass) return;
    const int* s = (r == 0) ? s0 : (r == 1) ? s1 : s2;
    int x = r * N_NODES + dd;
    int p = atomicAdd(&cur[x], 1) + bsum[x >> 10];
    eidx[p] = s[e];
}

// ---------------- per-node mean aggregation, all 3 relations per wave ----------------
__global__ void agg_kernel(const unsigned short* __restrict__ fb, const int* __restrict__ off,
                           const int* __restrict__ cnt, const int* __restrict__ bsum,
                           const int* __restrict__ eidx, unsigned short* __restrict__ agg) {
    int n = (blockIdx.x * blockDim.x + threadIdx.x) >> 6;
    int lane = threadIdx.x & 63;
    if (n >= N_NODES) return;
    const unsigned short* fbl = fb + lane * 4;

    int st3[3], dg3[3], e3[3];
    #pragma unroll
    for (int r = 0; r < 3; ++r) {
        int x = r * N_NODES + n;
        st3[r] = off[x] + bsum[x >> 10];
        dg3[r] = cnt[x];
    }
    #pragma unroll
    for (int r = 0; r < 3; ++r)                       // 3 head-loads in flight together
        e3[r] = (lane < dg3[r]) ? eidx[st3[r] + lane] : 0;

    #pragma unroll
    for (int r = 0; r < 3; ++r) {
        int deg = dg3[r], start = st3[r];
        float4 acc = make_float4(0.f, 0.f, 0.f, 0.f);
        for (int base = 0; base < deg; base += 64) {
            int m = min(deg - base, 64);
            int e = base ? ((lane < m) ? eidx[start + base + lane] : 0) : e3[r];
            int j = 0;
            for (; j + 7 < m; j += 8) {
                int t0 = __shfl(e, j + 0), t1 = __shfl(e, j + 1), t2 = __shfl(e, j + 2), t3 = __shfl(e, j + 3);
                int t4 = __shfl(e, j + 4), t5 = __shfl(e, j + 5), t6 = __shfl(e, j + 6), t7 = __shfl(e, j + 7);
                ushort4 v0 = *(const ushort4*)(fbl + (size_t)t0 * D);
                ushort4 v1 = *(const ushort4*)(fbl + (size_t)t1 * D);
                ushort4 v2 = *(const ushort4*)(fbl + (size_t)t2 * D);
                ushort4 v3 = *(const ushort4*)(fbl + (size_t)t3 * D);
                ushort4 v4 = *(const ushort4*)(fbl + (size_t)t4 * D);
                ushort4 v5 = *(const ushort4*)(fbl + (size_t)t5 * D);
                ushort4 v6 = *(const ushort4*)(fbl + (size_t)t6 * D);
                ushort4 v7 = *(const ushort4*)(fbl + (size_t)t7 * D);
                acc.x += ((bf2f(v0.x) + bf2f(v1.x)) + (bf2f(v2.x) + bf2f(v3.x))) + ((bf2f(v4.x) + bf2f(v5.x)) + (bf2f(v6.x) + bf2f(v7.x)));
                acc.y += ((bf2f(v0.y) + bf2f(v1.y)) + (bf2f(v2.y) + bf2f(v3.y))) + ((bf2f(v4.y) + bf2f(v5.y)) + (bf2f(v6.y) + bf2f(v7.y)));
                acc.z += ((bf2f(v0.z) + bf2f(v1.z)) + (bf2f(v2.z) + bf2f(v3.z))) + ((bf2f(v4.z) + bf2f(v5.z)) + (bf2f(v6.z) + bf2f(v7.z)));
                acc.w += ((bf2f(v0.w) + bf2f(v1.w)) + (bf2f(v2.w) + bf2f(v3.w))) + ((bf2f(v4.w) + bf2f(v5.w)) + (bf2f(v6.w) + bf2f(v7.w)));
            }
            for (; j < m; ++j) {
                int t = __shfl(e, j);
                ushort4 v = *(const ushort4*)(fbl + (size_t)t * D);
                acc.x += bf2f(v.x); acc.y += bf2f(v.y); acc.z += bf2f(v.z); acc.w += bf2f(v.w);
            }
        }
        float sc = (deg > 0) ? 1.0f / (float)deg : 0.0f;
        ushort4 pk;
        pk.x = f2bf(acc.x * sc);
        pk.y = f2bf(acc.y * sc);
        pk.z = f2bf(acc.z * sc);
        pk.w = f2bf(acc.w * sc);
        *(ushort4*)(agg + (((size_t)n * 3 + r) * D) + lane * 4) = pk;
    }
}

// ---------------- fused GEMM: out = relu( A[50000][768] @ B[768][256] + masked biases ) ----------------
// SINGLE-GENERATION design: 256x256 tiles, 512 threads (8 waves, 2x4), grid = 196
// blocks < 256 CUs -> all blocks concurrent, so even a full vmcnt drain per K-step
// costs only 24 serial drains (~15-30 us), not 3 generations of them.
// 3-buffer LDS (96 KB), unrolled K-loop, counted vmcnt; swizzle seg^((row>>1)&3).
__global__ __launch_bounds__(512) void gemm_kernel(
    const unsigned short* __restrict__ A, const unsigned short* __restrict__ BT,
    const int* __restrict__ cnt,
    const float* __restrict__ b0, const float* __restrict__ b1, const float* __restrict__ b2,
    float* __restrict__ out) {
    __shared__ __bf16 Asl[3][M_TILE][BK];   // 3 x 16 KB
    __shared__ __bf16 Bsl[3][N_TILE][BK];   // 3 x 16 KB
    int tid = threadIdx.x;
    int lane = tid & 63, w = tid >> 6;      // 8 waves
    int wr = w >> 2, wc = w & 3;            // wave tile: 128 rows x 64 cols
    int m0 = blockIdx.x * M_TILE;
    f32x4 acc[8][4] = {};

    // staging geometry: A tile = 1024 16B slots, B tile = 1024; thread does 2+2
    int s_lo = tid;                                      // slot 0..511
    int row_lo = s_lo >> 2, row_hi = (s_lo + 512) >> 2;
    int seg_lo = (s_lo & 3) ^ ((row_lo >> 1) & 3);       // inverse-swizzled global seg
    int seg_hi = (s_lo & 3) ^ ((row_hi >> 1) & 3);
    int gma = m0 + row_lo; if (gma >= N_NODES) gma = N_NODES - 1;
    int gmb = m0 + row_hi; if (gmb >= N_NODES) gmb = N_NODES - 1;
    const unsigned short* ga_lo = A + (size_t)gma * K_TOT + seg_lo * 8;
    const unsigned short* ga_hi = A + (size_t)gmb * K_TOT + seg_hi * 8;
    const unsigned short* gb_lo = BT + (size_t)row_lo * K_TOT + seg_lo * 8;
    const unsigned short* gb_hi = BT + (size_t)row_hi * K_TOT + seg_hi * 8;

    auto stage = [&](int kt, int b) {                    // b compile-time after unroll
        gload16(ga_lo + kt * BK, &Asl[b][0][0] + (size_t)s_lo * 8);
        gload16(ga_hi + kt * BK, &Asl[b][0][0] + (size_t)(s_lo + 512) * 8);
        gload16(gb_lo + kt * BK, &Bsl[b][0][0] + (size_t)s_lo * 8);
        gload16(gb_hi + kt * BK, &Bsl[b][0][0] + (size_t)(s_lo + 512) * 8);
    };

    stage(0, 0);
    stage(1, 1);
    int q = lane >> 4;
    int rr = lane & 15;
    #pragma unroll
    for (int kt = 0; kt < NKT; ++kt) {
        if (kt + 1 < NKT) asm volatile("s_waitcnt vmcnt(4)" ::: "memory");
        else              asm volatile("s_waitcnt vmcnt(0)" ::: "memory");
        __builtin_amdgcn_s_barrier();
        int b = kt % 3;
        bf16x8 af[8], bfr[4];
        #pragma unroll
        for (int mf = 0; mf < 8; ++mf) {
            int row = wr * 128 + mf * 16 + rr;
            af[mf] = *(const bf16x8*)&Asl[b][row][(q ^ ((row >> 1) & 3)) * 8];
        }
        #pragma unroll
        for (int nf = 0; nf < 4; ++nf) {
            int row = wc * 64 + nf * 16 + rr;
            bfr[nf] = *(const bf16x8*)&Bsl[b][row][(q ^ ((row >> 1) & 3)) * 8];
        }
        if (kt + 2 < NKT) stage(kt + 2, (kt + 2) % 3);
        #pragma unroll
        for (int mf = 0; mf < 8; ++mf)
            #pragma unroll
            for (int nf = 0; nf < 4; ++nf)
                acc[mf][nf] = __builtin_amdgcn_mfma_f32_16x16x32_bf16(af[mf], bfr[nf], acc[mf][nf], 0, 0, 0);
    }

    // epilogue: masked biases + relu; C/D layout: col = lane&15, row = (lane>>4)*4 + reg
    #pragma unroll
    for (int mf = 0; mf < 8; ++mf) {
        #pragma unroll
        for (int nf = 0; nf < 4; ++nf) {
            int col = wc * 64 + nf * 16 + rr;            // global col (N_TILE == D)
            #pragma unroll
            for (int reg = 0; reg < 4; ++reg) {
                int row = m0 + wr * 128 + mf * 16 + q * 4 + reg;
                if (row < N_NODES) {
                    float v = acc[mf][nf][reg];
                    if (cnt[row] > 0)               v += b0[col];
                    if (cnt[N_NODES + row] > 0)     v += b1[col];
                    if (cnt[2 * N_NODES + row] > 0) v += b2[col];
                    out[(size_t)row * D + col] = fmaxf(v, 0.0f);
                }
            }
        }
    }
}

extern "C" void kernel_launch(void* const* d_in, const int* in_sizes, int n_in,
                              void* d_out, int out_size, void* d_ws, size_t ws_size,
                              hipStream_t stream) {
    const float* feat = (const float*)d_in[0];
    const int* src0 = (const int*)d_in[1];
    const int* dst0 = (const int*)d_in[2];
    const int* src1 = (const int*)d_in[3];
    const int* dst1 = (const int*)d_in[4];
    const int* src2 = (const int*)d_in[5];
    const int* dst2 = (const int*)d_in[6];
    const float* W0 = (const float*)d_in[7];
    const float* b0 = (const float*)d_in[8];
    const float* W1 = (const float*)d_in[9];
    const float* b1 = (const float*)d_in[10];
    const float* W2 = (const float*)d_in[11];
    const float* b2 = (const float*)d_in[12];
    float* out = (float*)d_out;

    char* ws = (char*)d_ws;
    size_t o = 0;
    auto alloc = [&](size_t bytes) {
        size_t r = o;
        o += (bytes + 255) & ~(size_t)255;
        return r;
    };
    int* cnt            = (int*)(ws + alloc((size_t)SCAN_N * 4));
    int* off            = (int*)(ws + alloc((size_t)SCAN_N * 4));
    int* cur            = (int*)(ws + alloc((size_t)SCAN_N * 4));
    int* bsum           = (int*)(ws + alloc((size_t)SCAN_NBLK * 4));
    int* eidx           = (int*)(ws + alloc(3ull * N_EDGES * 4));
    unsigned short* WT  = (unsigned short*)(ws + alloc((size_t)D * K_TOT * 2));
    unsigned short* fb  = (unsigned short*)(ws + alloc((size_t)N_NODES * D * 2));
    unsigned short* agg = (unsigned short*)(ws + alloc(3ull * N_NODES * D * 2));

    prep_kernel<<<(N_NODES * D / 4 + 255) / 256, 256, 0, stream>>>(feat, fb, W0, W1, W2, WT, cnt);
    count_kernel<<<(3 * N_EDGES + 255) / 256, 256, 0, stream>>>(dst0, dst1, dst2, cnt);
    scan1_kernel<<<SCAN_NBLK, 1024, 0, stream>>>(cnt, off, cur, bsum);
    scan2_kernel<<<1, 1024, 0, stream>>>(bsum);
    dim3 fg((3 * N_EDGES + 255) / 256, NPASS);
    fill_kernel<<<fg, 256, 0, stream>>>(src0, dst0, src1, dst1, src2, dst2, cur, bsum, eidx);
    agg_kernel<<<(N_NODES * 64 + 255) / 256, 256, 0, stream>>>(fb, off, cnt, bsum, eidx, agg);
    gemm_kernel<<<NMB, 512, 0, stream>>>(agg, WT, cnt, b0, b1, b2, out);
}